// Round 1
// baseline (1201.967 us; speedup 1.0000x reference)
//
#include <hip/hip_runtime.h>
#include <stdint.h>

#define Bdim 32
#define Tdim 12
#define Vdim 1024
#define Edim 64
#define Gdim 32
#define BT   384   // B*T

// ---------------------------------------------------------------------------
// K1: Xt[e][bt][i] = inputs[bt][i][e]   (f32 transpose for unit-stride K)
// ---------------------------------------------------------------------------
__global__ __launch_bounds__(256) void k_transpose(const float* __restrict__ in,
                                                   float* __restrict__ Xt) {
    __shared__ float tile[64][68];               // pad 68 keeps 16B alignment
    const int bt = blockIdx.x >> 4;
    const int i0 = (blockIdx.x & 15) << 6;
    const int r  = threadIdx.x >> 2;             // 0..63
    const int q  = threadIdx.x & 3;              // 0..3
    const float* src = in + ((size_t)(bt * Vdim + i0 + r)) * Edim + q * 16;
#pragma unroll
    for (int k = 0; k < 4; ++k) {
        float4 x = *(const float4*)(src + 4 * k);
        *(float4*)&tile[r][q * 16 + 4 * k] = x;  // tile[i_local][e]
    }
    __syncthreads();
    float* dst = Xt + ((size_t)r * BT + bt) * Vdim + i0 + q * 16;  // e = r
#pragma unroll
    for (int k = 0; k < 4; ++k) {
        float4 x;
        x.x = tile[q * 16 + 4 * k + 0][r];
        x.y = tile[q * 16 + 4 * k + 1][r];
        x.z = tile[q * 16 + 4 * k + 2][r];
        x.w = tile[q * 16 + 4 * k + 3][r];
        *(float4*)(dst + 4 * k) = x;
    }
}

// ---------------------------------------------------------------------------
// K2: x_rel[bt][v][e] = sum_i relu(sum_g srpe[v,g,e]*srpe[i,g,e]) * X_e[bt][i]
// One workgroup: fixed e, 64 v, all 384 bt, K-loop over i (KI=16).
// Relation tile recomputed in-kernel (no V*V*E intermediate).
// Writes x_rel into d_out (same shape as final output).
// ---------------------------------------------------------------------------
template<int USE_XT>
__global__ __launch_bounds__(256) void k_relmix(const float* __restrict__ srpe,
                                                const float* __restrict__ X,
                                                float* __restrict__ out) {
    __shared__ float A_lds[16][384];   // [ii][bt]
    __shared__ float B_lds[16][64];    // [ii][v]  (relu'd relation)
    __shared__ float sv[64][33];       // srpe[v0+vv][g][e]
    __shared__ float si[32][16];       // srpe[i0+ii][g][e], layout [g][ii]

    const int tid = threadIdx.x;
    const int e   = blockIdx.x & 63;
    const int v0  = (blockIdx.x >> 6) << 6;

    {   // load sv once per workgroup
        const int vv = tid >> 2;
        const int g0 = (tid & 3) * 8;
#pragma unroll
        for (int k = 0; k < 8; ++k)
            sv[vv][g0 + k] = srpe[((size_t)(v0 + vv) * Gdim + g0 + k) * Edim + e];
    }

    float acc[6][16];
#pragma unroll
    for (int j = 0; j < 6; ++j)
#pragma unroll
        for (int k = 0; k < 16; ++k) acc[j][k] = 0.f;

    const int btg = tid >> 2;     // 0..63 (bt = btg + 64*j)
    const int vg  = tid & 3;      // v group of 16
    const int vR  = tid & 63;     // v for relation compute
    const int iig = tid >> 6;     // 0..3

    for (int i0 = 0; i0 < Vdim; i0 += 16) {
        __syncthreads();
        // stage si[g][ii]
#pragma unroll
        for (int k = 0; k < 2; ++k) {
            int idx = tid * 2 + k;
            int ii = idx >> 5, g = idx & 31;
            si[g][ii] = srpe[((size_t)(i0 + ii) * Gdim + g) * Edim + e];
        }
        // stage A_lds[ii][bt]
        if (USE_XT) {
#pragma unroll
            for (int c = 0; c < 6; ++c) {
                int flat = (c * 256 + tid) * 4;
                int bt = flat >> 4, ii = flat & 15;
                float4 x = *(const float4*)(X + ((size_t)e * BT + bt) * Vdim + i0 + ii);
                A_lds[ii + 0][bt] = x.x; A_lds[ii + 1][bt] = x.y;
                A_lds[ii + 2][bt] = x.z; A_lds[ii + 3][bt] = x.w;
            }
        } else {  // fallback: strided gather straight from inputs
#pragma unroll
            for (int c = 0; c < 6; ++c) {
                int flat = (c * 256 + tid) * 4;
                int bt = flat >> 4, ii = flat & 15;
#pragma unroll
                for (int k = 0; k < 4; ++k)
                    A_lds[ii + k][bt] = X[((size_t)bt * Vdim + i0 + ii + k) * Edim + e];
            }
        }
        __syncthreads();
        // relation tile: R[ii][v] = relu(sum_g sv[v][g]*si[ii][g])
        float r4[4] = {0.f, 0.f, 0.f, 0.f};
#pragma unroll
        for (int g = 0; g < 32; ++g) {
            float  svv = sv[vR][g];
            float4 s4  = *(const float4*)&si[g][iig * 4];
            r4[0] += svv * s4.x; r4[1] += svv * s4.y;
            r4[2] += svv * s4.z; r4[3] += svv * s4.w;
        }
#pragma unroll
        for (int k = 0; k < 4; ++k)
            B_lds[iig * 4 + k][vR] = fmaxf(r4[k], 0.f);
        __syncthreads();
        // main FMA: acc[bt][v] += A[bt][ii] * R[ii][v]
#pragma unroll
        for (int ii = 0; ii < 16; ++ii) {
            float bb[16];
#pragma unroll
            for (int k = 0; k < 16; k += 4) {
                float4 b4 = *(const float4*)&B_lds[ii][vg * 16 + k];
                bb[k] = b4.x; bb[k + 1] = b4.y; bb[k + 2] = b4.z; bb[k + 3] = b4.w;
            }
            float aa[6];
#pragma unroll
            for (int j = 0; j < 6; ++j) aa[j] = A_lds[ii][btg + 64 * j];
#pragma unroll
            for (int j = 0; j < 6; ++j)
#pragma unroll
                for (int k = 0; k < 16; ++k)
                    acc[j][k] += aa[j] * bb[k];
        }
    }
    // store x_rel into d_out
#pragma unroll
    for (int j = 0; j < 6; ++j) {
        const int bt = btg + 64 * j;
        float* dst = out + ((size_t)bt * Vdim + v0 + vg * 16) * Edim + e;
#pragma unroll
        for (int k = 0; k < 16; ++k)
            dst[(size_t)k * Edim] = acc[j][k];
    }
}

// ---------------------------------------------------------------------------
// K3: per (t,v): y[b,e] = leaky( sum_f xl[b,f] * W[t,v,f,e] + bias[t,v,e] )
// xl = [x_rel (from d_out) | sape gather | dow+tod gather]; in-place on d_out.
// ---------------------------------------------------------------------------
__global__ __launch_bounds__(256) void k_final(const float* xrel,
        const int* __restrict__ n_route, const int* __restrict__ s_week,
        const int* __restrict__ s_day,  const float* __restrict__ sape,
        const float* __restrict__ dow,  const float* __restrict__ tod,
        const float* __restrict__ Wc,   const float* __restrict__ bias,
        float* out) {
    __shared__ float Wl[192 * 64];     // also reused as reduction buffer
    __shared__ float xl[32][197];      // pad 197: conflict-free b-strided reads
    const int tid = threadIdx.x;
    const int v = blockIdx.x & (Vdim - 1);
    const int t = blockIdx.x >> 10;

    const float* Wg = Wc + ((size_t)(t * Vdim + v)) * 192 * Edim;
#pragma unroll
    for (int it = 0; it < 12; ++it) {
        int off = (it * 256 + tid) * 4;
        *(float4*)&Wl[off] = *(const float4*)(Wg + off);
    }
    {   // build xl[b][0:192]
        const int b  = tid >> 3;
        const int e0 = (tid & 7) * 8;
        const int bt = b * Tdim + t;
        const float* xr = xrel + ((size_t)bt * Vdim + v) * Edim + e0;
        const int r  = n_route[b * Vdim + v];
        const float* sp = sape + ((size_t)r * Tdim + t) * Edim + e0;
        const int wd = s_week[bt];
        const int dd = s_day[bt];
        const float* dp = dow + ((size_t)wd * Vdim + v) * Edim + e0;
        const float* tp = tod + ((size_t)dd * Vdim + v) * Edim + e0;
#pragma unroll
        for (int k = 0; k < 8; ++k) {
            xl[b][e0 + k]        = xr[k];
            xl[b][64 + e0 + k]   = sp[k];
            xl[b][128 + e0 + k]  = dp[k] + tp[k];
        }
    }
    __syncthreads();
    const int wave = tid >> 6;            // f-split: 4 waves x 48 f
    const int lane = tid & 63;
    const int b0 = (lane >> 2) * 2;
    const int e0 = (lane & 3) * 16;
    float acc[2][16];
#pragma unroll
    for (int j = 0; j < 2; ++j)
#pragma unroll
        for (int k = 0; k < 16; ++k) acc[j][k] = 0.f;
    const int f0 = wave * 48;
#pragma unroll 4
    for (int f = f0; f < f0 + 48; ++f) {
        float x0 = xl[b0][f];
        float x1 = xl[b0 + 1][f];
        float ww[16];
#pragma unroll
        for (int k = 0; k < 16; k += 4) {
            float4 w4 = *(const float4*)&Wl[f * 64 + e0 + k];
            ww[k] = w4.x; ww[k + 1] = w4.y; ww[k + 2] = w4.z; ww[k + 3] = w4.w;
        }
#pragma unroll
        for (int k = 0; k < 16; ++k) {
            acc[0][k] += x0 * ww[k];
            acc[1][k] += x1 * ww[k];
        }
    }
    __syncthreads();   // everyone done reading Wl -> reuse as partial buffer
#pragma unroll
    for (int j = 0; j < 2; ++j)
#pragma unroll
        for (int k = 0; k < 16; ++k)
            Wl[wave * 2048 + (b0 + j) * 64 + e0 + k] = acc[j][k];
    __syncthreads();
    {
        const int b   = tid >> 3;
        const int e0o = (tid & 7) * 8;
        const size_t obase = ((size_t)(b * Tdim + t) * Vdim + v) * Edim;
        const float* bs = bias + ((size_t)(t * Vdim + v)) * Edim;
#pragma unroll
        for (int k = 0; k < 8; ++k) {
            int e = e0o + k;
            float s = Wl[b * 64 + e] + Wl[2048 + b * 64 + e]
                    + Wl[4096 + b * 64 + e] + Wl[6144 + b * 64 + e] + bs[e];
            out[obase + e] = s > 0.f ? s : 0.3f * s;
        }
    }
}

// ---------------------------------------------------------------------------
extern "C" void kernel_launch(void* const* d_in, const int* in_sizes, int n_in,
                              void* d_out, int out_size, void* d_ws, size_t ws_size,
                              hipStream_t stream) {
    const float* inputs = (const float*)d_in[0];
    const int*   n_route= (const int*)d_in[1];
    const int*   s_week = (const int*)d_in[2];
    const int*   s_day  = (const int*)d_in[3];
    const float* srpe   = (const float*)d_in[4];
    const float* sape   = (const float*)d_in[5];
    const float* dow    = (const float*)d_in[6];
    const float* tod    = (const float*)d_in[7];
    const float* Wc     = (const float*)d_in[8];
    const float* bias   = (const float*)d_in[9];
    float* out = (float*)d_out;
    float* Xt  = (float*)d_ws;

    const size_t xt_bytes = (size_t)Edim * BT * Vdim * sizeof(float);  // 100 MB
    if (ws_size >= xt_bytes) {
        k_transpose<<<dim3(384 * 16), dim3(256), 0, stream>>>(inputs, Xt);
        k_relmix<1><<<dim3(64 * 16), dim3(256), 0, stream>>>(srpe, Xt, out);
    } else {
        k_relmix<0><<<dim3(64 * 16), dim3(256), 0, stream>>>(srpe, inputs, out);
    }
    k_final<<<dim3(Tdim * Vdim), dim3(256), 0, stream>>>(
        out, n_route, s_week, s_day, sape, dow, tod, Wc, bias, out);
}

// Round 2
// 365.057 us; speedup vs baseline: 3.2925x; 3.2925x over previous
//
#include <hip/hip_runtime.h>
#include <stdint.h>

#define Bdim 32
#define Tdim 12
#define Vdim 1024
#define Edim 64
#define Gdim 32
#define BT   384   // B*T

typedef __attribute__((ext_vector_type(8))) short bf16x8;
typedef __attribute__((ext_vector_type(4))) float f32x4;

__device__ __forceinline__ ushort f2bf(float f) {
    uint u = __float_as_uint(f);
    u += 0x7fffu + ((u >> 16) & 1u);      // RNE
    return (ushort)(u >> 16);
}
__device__ __forceinline__ float bf2f_lo(uint u) { return __uint_as_float(u << 16); }
__device__ __forceinline__ float bf2f_hi(uint u) { return __uint_as_float(u & 0xffff0000u); }
__device__ __forceinline__ uint pk2(float a, float b) {
    return (uint)f2bf(a) | ((uint)f2bf(b) << 16);
}

// ---------------------------------------------------------------------------
// K1a: Xbf[e][bt][i] (bf16) = inputs[bt][i][e] (f32)
// ---------------------------------------------------------------------------
__global__ __launch_bounds__(256) void k_xpose(const float* __restrict__ in,
                                               ushort* __restrict__ Xbf) {
    __shared__ float tile[64][68];
    const int bt = blockIdx.x >> 4;
    const int i0 = (blockIdx.x & 15) << 6;
    const int r  = threadIdx.x >> 2;     // i-local on load, e on store
    const int q  = threadIdx.x & 3;
    const float* src = in + ((size_t)(bt * Vdim) + i0 + r) * Edim + q * 16;
#pragma unroll
    for (int k = 0; k < 4; ++k)
        *(float4*)&tile[r][q * 16 + 4 * k] = *(const float4*)(src + 4 * k);
    __syncthreads();
    const int e  = r;
    const int ib = q * 16;
    uint4 s0, s1;
    s0.x = pk2(tile[ib + 0][e],  tile[ib + 1][e]);
    s0.y = pk2(tile[ib + 2][e],  tile[ib + 3][e]);
    s0.z = pk2(tile[ib + 4][e],  tile[ib + 5][e]);
    s0.w = pk2(tile[ib + 6][e],  tile[ib + 7][e]);
    s1.x = pk2(tile[ib + 8][e],  tile[ib + 9][e]);
    s1.y = pk2(tile[ib + 10][e], tile[ib + 11][e]);
    s1.z = pk2(tile[ib + 12][e], tile[ib + 13][e]);
    s1.w = pk2(tile[ib + 14][e], tile[ib + 15][e]);
    ushort* dst = Xbf + ((size_t)(e * BT) + bt) * Vdim + i0 + ib;
    *(uint4*)dst = s0;
    *(uint4*)(dst + 8) = s1;
}

// ---------------------------------------------------------------------------
// K1b: Se[e][v][g] (bf16) = srpe[v][g][e] (f32)
// ---------------------------------------------------------------------------
__global__ __launch_bounds__(256) void k_se(const float* __restrict__ srpe,
                                            ushort* __restrict__ Se) {
    __shared__ float t2[256][65];        // [vv*32+g][e], pad 65
    const int tid = threadIdx.x;
    const int v0 = blockIdx.x * 8;
#pragma unroll
    for (int c = 0; c < 16; ++c) {
        int f = (c * 256 + tid) * 4;     // flat f32 idx within block slab
        int vg = f >> 6;
        int e4 = f & 63;
        *(float4*)&t2[vg][e4] = *(const float4*)(srpe + (size_t)v0 * Gdim * Edim + f);
    }
    __syncthreads();
    const int e = tid & 63;
#pragma unroll
    for (int h = 0; h < 2; ++h) {
        const int vv = (tid >> 6) * 2 + h;
        uint4 o[2];
#pragma unroll
        for (int c = 0; c < 2; ++c) {
            o[c].x = pk2(t2[vv * 32 + c * 16 + 0][e],  t2[vv * 32 + c * 16 + 1][e]);
            o[c].y = pk2(t2[vv * 32 + c * 16 + 2][e],  t2[vv * 32 + c * 16 + 3][e]);
            o[c].z = pk2(t2[vv * 32 + c * 16 + 4][e],  t2[vv * 32 + c * 16 + 5][e]);
            o[c].w = pk2(t2[vv * 32 + c * 16 + 6][e],  t2[vv * 32 + c * 16 + 7][e]);
        }
        uint4 o2[2];
#pragma unroll
        for (int c = 0; c < 2; ++c) {
            o2[c].x = pk2(t2[vv * 32 + c * 16 + 8][e],  t2[vv * 32 + c * 16 + 9][e]);
            o2[c].y = pk2(t2[vv * 32 + c * 16 + 10][e], t2[vv * 32 + c * 16 + 11][e]);
            o2[c].z = pk2(t2[vv * 32 + c * 16 + 12][e], t2[vv * 32 + c * 16 + 13][e]);
            o2[c].w = pk2(t2[vv * 32 + c * 16 + 14][e], t2[vv * 32 + c * 16 + 15][e]);
        }
        ushort* dst = Se + ((size_t)(e * Vdim) + v0 + vv) * Gdim;
        *(uint4*)(dst + 0)  = o[0];
        *(uint4*)(dst + 8)  = o2[0];
        *(uint4*)(dst + 16) = o[1];
        *(uint4*)(dst + 24) = o2[1];
    }
}

// ---------------------------------------------------------------------------
// K2: MFMA graph-mix.  Per wg: fixed e, 192 bt x 128 v, K over i (step 32).
// Relation tile R[v][i] = relu(Si . Sv^T) computed per step with MFMA.
// Output: xrel bf16 [e][bt][v] into d_out.
// ---------------------------------------------------------------------------
__global__ __launch_bounds__(256) void k_relmix_mfma(const ushort* __restrict__ Xbf,
                                                     const ushort* __restrict__ Se,
                                                     ushort* __restrict__ xrel) {
    __shared__ __align__(16) ushort A_s[192 * 32];   // [bt][i] rows 64 B (gll linear)
    __shared__ __align__(16) ushort Sv_s[128 * 32];  // [v][g]  rows 64 B (gll linear)
    __shared__ __align__(16) ushort Si_s[32 * 32];   // [i][g]  rows 64 B (gll linear)
    __shared__ __align__(16) ushort R_s[128 * 40];   // [v][i]  rows 80 B (pad: 2-way banks)

    const int tid = threadIdx.x;
    const int l = tid & 63;
    const int w = tid >> 6;              // wave 0..3
    const int wm = w >> 1;               // bt half (96 each)
    const int wn = w & 1;                // v half (64 each)

    const int btT = blockIdx.x >> 3;
    const int vT  = blockIdx.x & 7;
    const int e   = blockIdx.y;
    const int bt0 = btT * 192;
    const int v0  = vT * 128;

    // stage Sv once (8 KB, linear)
    {
        const ushort* gSv = Se + ((size_t)e * Vdim + v0) * Gdim;
#pragma unroll
        for (int c = 0; c < 2; ++c) {
            int chunk = w * 2 + c;
            const ushort* g = gSv + (size_t)(chunk * 16 + (l >> 2)) * Gdim + (l & 3) * 8;
            __builtin_amdgcn_global_load_lds(g, &Sv_s[chunk * 512], 16, 0, 0);
        }
    }

    f32x4 acc[6][4];
    const f32x4 fz = {0.f, 0.f, 0.f, 0.f};
#pragma unroll
    for (int m = 0; m < 6; ++m)
#pragma unroll
        for (int n = 0; n < 4; ++n) acc[m][n] = fz;

    const ushort* gA = Xbf + ((size_t)(e * BT + bt0)) * Vdim;

    for (int i0 = 0; i0 < Vdim; i0 += 32) {
        // ---- stage A tile (192x32 bf16 = 12 KB) + Si tile (32x32 = 2 KB)
#pragma unroll
        for (int c = 0; c < 3; ++c) {
            int chunk = w * 3 + c;       // 16 rows each
            const ushort* g = gA + (size_t)(chunk * 16 + (l >> 2)) * Vdim + i0 + (l & 3) * 8;
            __builtin_amdgcn_global_load_lds(g, &A_s[chunk * 512], 16, 0, 0);
        }
        if (w < 2) {
            const ushort* g = Se + ((size_t)e * Vdim + i0 + w * 16 + (l >> 2)) * Gdim + (l & 3) * 8;
            __builtin_amdgcn_global_load_lds(g, &Si_s[w * 512], 16, 0, 0);
        }
        __syncthreads();                 // drains vmcnt+lgkm

        // ---- relation: wave w computes v cols [32w, 32w+32), i rows 0..32
        {
            bf16x8 siF0 = *(const bf16x8*)&Si_s[((l & 15)) * 32 + (l >> 4) * 8];
            bf16x8 siF1 = *(const bf16x8*)&Si_s[(16 + (l & 15)) * 32 + (l >> 4) * 8];
#pragma unroll
            for (int k = 0; k < 2; ++k) {
                const int vloc = (2 * w + k) * 16 + (l & 15);
                bf16x8 svF = *(const bf16x8*)&Sv_s[vloc * 32 + (l >> 4) * 8];
                f32x4 d0 = __builtin_amdgcn_mfma_f32_16x16x32_bf16(siF0, svF, fz, 0, 0, 0);
                f32x4 d1 = __builtin_amdgcn_mfma_f32_16x16x32_bf16(siF1, svF, fz, 0, 0, 0);
                const int ib0 = (l >> 4) * 4;            // i row base, tile 0
                uint2 w0, w1;
                w0.x = pk2(fmaxf(d0[0], 0.f), fmaxf(d0[1], 0.f));
                w0.y = pk2(fmaxf(d0[2], 0.f), fmaxf(d0[3], 0.f));
                w1.x = pk2(fmaxf(d1[0], 0.f), fmaxf(d1[1], 0.f));
                w1.y = pk2(fmaxf(d1[2], 0.f), fmaxf(d1[3], 0.f));
                *(uint2*)&R_s[vloc * 40 + ib0]      = w0;
                *(uint2*)&R_s[vloc * 40 + 16 + ib0] = w1;
            }
        }

        // ---- main A fragments (A_s stable until next stage)
        bf16x8 aF[6];
#pragma unroll
        for (int m = 0; m < 6; ++m)
            aF[m] = *(const bf16x8*)&A_s[(wm * 96 + m * 16 + (l & 15)) * 32 + (l >> 4) * 8];
        __syncthreads();                 // R_s ready

        // ---- 24 MFMAs
#pragma unroll
        for (int n = 0; n < 4; ++n) {
            bf16x8 bF = *(const bf16x8*)&R_s[(wn * 64 + n * 16 + (l & 15)) * 40 + (l >> 4) * 8];
#pragma unroll
            for (int m = 0; m < 6; ++m)
                acc[m][n] = __builtin_amdgcn_mfma_f32_16x16x32_bf16(aF[m], bF, acc[m][n], 0, 0, 0);
        }
    }

    // ---- epilogue: bf16 stores, v-contiguous across lanes (32 B runs)
#pragma unroll
    for (int m = 0; m < 6; ++m) {
        const int btl = bt0 + wm * 96 + m * 16 + (l >> 4) * 4;
#pragma unroll
        for (int j = 0; j < 4; ++j) {
            ushort* row = xrel + ((size_t)(e * BT) + btl + j) * Vdim + v0;
#pragma unroll
            for (int n = 0; n < 4; ++n)
                row[wn * 64 + n * 16 + (l & 15)] = f2bf(acc[m][n][j]);
        }
    }
}

// ---------------------------------------------------------------------------
// K2.5: xrT[bt][v][e] = xrel[e][bt][v]   (bf16 -> bf16, XOR-swizzled LDS)
// ---------------------------------------------------------------------------
__global__ __launch_bounds__(256) void k_xrelT(const ushort* __restrict__ xr,
                                               ushort* __restrict__ xrT) {
    __shared__ uint t[64 * 256];         // word (e, vpair), swizzled
    const int tid = threadIdx.x;
    const int bt = blockIdx.x >> 1;
    const int v0 = (blockIdx.x & 1) * 512;
    {
        const int e = tid >> 2, q = tid & 3;
        const ushort* src = xr + ((size_t)(e * BT) + bt) * Vdim + v0 + q * 128;
#pragma unroll
        for (int c = 0; c < 16; ++c) {
            uint4 x = *(const uint4*)(src + c * 8);
            int p = q * 64 + c * 4;
            int sw = ((e & 3) << 3) ^ ((p >> 6) << 2);
            *(uint4*)&t[e * 256 + (p ^ sw)] = x;
        }
    }
    __syncthreads();
    {
        const int p = tid;               // v-pair 0..255
        uint lw[32], hw[32];
#pragma unroll
        for (int e2 = 0; e2 < 32; ++e2) {
            const int ea = 2 * e2, eb = 2 * e2 + 1;
            uint xa = t[ea * 256 + (p ^ (((ea & 3) << 3) ^ ((p >> 6) << 2)))];
            uint xb = t[eb * 256 + (p ^ (((eb & 3) << 3) ^ ((p >> 6) << 2)))];
            lw[e2] = (xa & 0xffffu) | (xb << 16);
            hw[e2] = (xa >> 16) | (xb & 0xffff0000u);
        }
        ushort* d0 = xrT + ((size_t)(bt * Vdim) + v0 + 2 * p) * Edim;
        ushort* d1 = d0 + Edim;
#pragma unroll
        for (int c = 0; c < 8; ++c) {
            uint4 o; o.x = lw[c*4]; o.y = lw[c*4+1]; o.z = lw[c*4+2]; o.w = lw[c*4+3];
            *(uint4*)(d0 + c * 8) = o;
        }
#pragma unroll
        for (int c = 0; c < 8; ++c) {
            uint4 o; o.x = hw[c*4]; o.y = hw[c*4+1]; o.z = hw[c*4+2]; o.w = hw[c*4+3];
            *(uint4*)(d1 + c * 8) = o;
        }
    }
}

// ---------------------------------------------------------------------------
// K3: per (t,v): y[b,e] = leaky( sum_f xl[b,f] * W[t,v,f,e] + bias )
// ---------------------------------------------------------------------------
__global__ __launch_bounds__(256) void k_final(const ushort* __restrict__ xrT,
        const int* __restrict__ n_route, const int* __restrict__ s_week,
        const int* __restrict__ s_day,  const float* __restrict__ sape,
        const float* __restrict__ dow,  const float* __restrict__ tod,
        const float* __restrict__ Wc,   const float* __restrict__ bias,
        float* __restrict__ out) {
    __shared__ float Wl[192 * 64];
    __shared__ float xl[32][197];
    const int tid = threadIdx.x;
    const int v = blockIdx.x & (Vdim - 1);
    const int t = blockIdx.x >> 10;

    const float* Wg = Wc + ((size_t)(t * Vdim + v)) * 192 * Edim;
#pragma unroll
    for (int it = 0; it < 12; ++it) {
        int off = (it * 256 + tid) * 4;
        *(float4*)&Wl[off] = *(const float4*)(Wg + off);
    }
    {
        const int b  = tid >> 3;
        const int e0 = (tid & 7) * 8;
        const int bt = b * Tdim + t;
        const ushort* xp = xrT + ((size_t)(bt * Vdim) + v) * Edim + e0;
        uint4 raw = *(const uint4*)xp;
        xl[b][e0 + 0] = bf2f_lo(raw.x); xl[b][e0 + 1] = bf2f_hi(raw.x);
        xl[b][e0 + 2] = bf2f_lo(raw.y); xl[b][e0 + 3] = bf2f_hi(raw.y);
        xl[b][e0 + 4] = bf2f_lo(raw.z); xl[b][e0 + 5] = bf2f_hi(raw.z);
        xl[b][e0 + 6] = bf2f_lo(raw.w); xl[b][e0 + 7] = bf2f_hi(raw.w);
        const int r  = n_route[b * Vdim + v];
        const float* sp = sape + ((size_t)(r * Tdim) + t) * Edim + e0;
        const int wd = s_week[bt];
        const int dd = s_day[bt];
        const float* dp = dow + ((size_t)(wd * Vdim) + v) * Edim + e0;
        const float* tp = tod + ((size_t)(dd * Vdim) + v) * Edim + e0;
#pragma unroll
        for (int k = 0; k < 8; ++k) {
            xl[b][64 + e0 + k]  = sp[k];
            xl[b][128 + e0 + k] = dp[k] + tp[k];
        }
    }
    __syncthreads();
    const int wave = tid >> 6;
    const int lane = tid & 63;
    const int b0 = (lane >> 2) * 2;
    const int e0 = (lane & 3) * 16;
    float acc[2][16];
#pragma unroll
    for (int j = 0; j < 2; ++j)
#pragma unroll
        for (int k = 0; k < 16; ++k) acc[j][k] = 0.f;
    const int f0 = wave * 48;
#pragma unroll 4
    for (int f = f0; f < f0 + 48; ++f) {
        float x0 = xl[b0][f];
        float x1 = xl[b0 + 1][f];
        float ww[16];
#pragma unroll
        for (int k = 0; k < 16; k += 4) {
            float4 w4 = *(const float4*)&Wl[f * 64 + e0 + k];
            ww[k] = w4.x; ww[k + 1] = w4.y; ww[k + 2] = w4.z; ww[k + 3] = w4.w;
        }
#pragma unroll
        for (int k = 0; k < 16; ++k) {
            acc[0][k] += x0 * ww[k];
            acc[1][k] += x1 * ww[k];
        }
    }
    __syncthreads();
#pragma unroll
    for (int j = 0; j < 2; ++j)
#pragma unroll
        for (int k = 0; k < 16; ++k)
            Wl[wave * 2048 + (b0 + j) * 64 + e0 + k] = acc[j][k];
    __syncthreads();
    {
        const int b   = tid >> 3;
        const int e0o = (tid & 7) * 8;
        const size_t obase = ((size_t)(b * Tdim + t) * Vdim + v) * Edim;
        const float* bs = bias + ((size_t)(t * Vdim + v)) * Edim;
#pragma unroll
        for (int k = 0; k < 8; ++k) {
            int e = e0o + k;
            float s = Wl[b * 64 + e] + Wl[2048 + b * 64 + e]
                    + Wl[4096 + b * 64 + e] + Wl[6144 + b * 64 + e] + bs[e];
            out[obase + e] = s > 0.f ? s : 0.3f * s;
        }
    }
}

// ---------------------------------------------------------------------------
extern "C" void kernel_launch(void* const* d_in, const int* in_sizes, int n_in,
                              void* d_out, int out_size, void* d_ws, size_t ws_size,
                              hipStream_t stream) {
    const float* inputs = (const float*)d_in[0];
    const int*   n_route= (const int*)d_in[1];
    const int*   s_week = (const int*)d_in[2];
    const int*   s_day  = (const int*)d_in[3];
    const float* srpe   = (const float*)d_in[4];
    const float* sape   = (const float*)d_in[5];
    const float* dow    = (const float*)d_in[6];
    const float* tod    = (const float*)d_in[7];
    const float* Wc     = (const float*)d_in[8];
    const float* bias   = (const float*)d_in[9];

    // ws layout: Xbf [0, 48MB) ; Se [48MB, 52MB) ; xrT reuses [0, 48MB) after K2
    ushort* Xbf  = (ushort*)d_ws;
    ushort* Se   = (ushort*)((char*)d_ws + (size_t)Edim * BT * Vdim * 2);
    ushort* xrel = (ushort*)d_out;               // bf16 scratch inside d_out
    ushort* xrT  = (ushort*)d_ws;                // overwrites Xbf (dead after K2)
    float*  out  = (float*)d_out;

    k_xpose<<<dim3(BT * 16), dim3(256), 0, stream>>>(inputs, Xbf);
    k_se<<<dim3(Vdim / 8), dim3(256), 0, stream>>>(srpe, Se);
    k_relmix_mfma<<<dim3(16, 64), dim3(256), 0, stream>>>(Xbf, Se, xrel);
    k_xrelT<<<dim3(BT * 2), dim3(256), 0, stream>>>(xrel, xrT);
    k_final<<<dim3(Tdim * Vdim), dim3(256), 0, stream>>>(
        xrT, n_route, s_week, s_day, sape, dow, tod, Wc, bias, out);
}

// Round 3
// 324.455 us; speedup vs baseline: 3.7046x; 1.1251x over previous
//
#include <hip/hip_runtime.h>
#include <stdint.h>

#define Bdim 32
#define Tdim 12
#define Vdim 1024
#define Edim 64
#define Gdim 32
#define BT   384   // B*T

typedef __attribute__((ext_vector_type(8))) short bf16x8;
typedef __attribute__((ext_vector_type(4))) float f32x4;

__device__ __forceinline__ ushort f2bf(float f) {
    uint u = __float_as_uint(f);
    u += 0x7fffu + ((u >> 16) & 1u);      // RNE
    return (ushort)(u >> 16);
}
__device__ __forceinline__ float bf2f_lo(uint u) { return __uint_as_float(u << 16); }
__device__ __forceinline__ float bf2f_hi(uint u) { return __uint_as_float(u & 0xffff0000u); }
__device__ __forceinline__ uint pk2(float a, float b) {
    return (uint)f2bf(a) | ((uint)f2bf(b) << 16);
}

// ---------------------------------------------------------------------------
// K1a: Xbf[e][bt][i] (bf16) = inputs[bt][i][e] (f32)
// ---------------------------------------------------------------------------
__global__ __launch_bounds__(256) void k_xpose(const float* __restrict__ in,
                                               ushort* __restrict__ Xbf) {
    __shared__ float tile[64][68];
    const int bt = blockIdx.x >> 4;
    const int i0 = (blockIdx.x & 15) << 6;
    const int r  = threadIdx.x >> 2;     // i-local on load, e on store
    const int q  = threadIdx.x & 3;
    const float* src = in + ((size_t)(bt * Vdim) + i0 + r) * Edim + q * 16;
#pragma unroll
    for (int k = 0; k < 4; ++k)
        *(float4*)&tile[r][q * 16 + 4 * k] = *(const float4*)(src + 4 * k);
    __syncthreads();
    const int e  = r;
    const int ib = q * 16;
    uint4 s0, s1;
    s0.x = pk2(tile[ib + 0][e],  tile[ib + 1][e]);
    s0.y = pk2(tile[ib + 2][e],  tile[ib + 3][e]);
    s0.z = pk2(tile[ib + 4][e],  tile[ib + 5][e]);
    s0.w = pk2(tile[ib + 6][e],  tile[ib + 7][e]);
    s1.x = pk2(tile[ib + 8][e],  tile[ib + 9][e]);
    s1.y = pk2(tile[ib + 10][e], tile[ib + 11][e]);
    s1.z = pk2(tile[ib + 12][e], tile[ib + 13][e]);
    s1.w = pk2(tile[ib + 14][e], tile[ib + 15][e]);
    ushort* dst = Xbf + ((size_t)(e * BT) + bt) * Vdim + i0 + ib;
    *(uint4*)dst = s0;
    *(uint4*)(dst + 8) = s1;
}

// ---------------------------------------------------------------------------
// K1b: Se[e][v][g] (bf16) = srpe[v][g][e] (f32)
// ---------------------------------------------------------------------------
__global__ __launch_bounds__(256) void k_se(const float* __restrict__ srpe,
                                            ushort* __restrict__ Se) {
    __shared__ float t2[256][65];        // [vv*32+g][e], pad 65
    const int tid = threadIdx.x;
    const int v0 = blockIdx.x * 8;
#pragma unroll
    for (int c = 0; c < 16; ++c) {
        int f = (c * 256 + tid) * 4;     // flat f32 idx within block slab
        int vg = f >> 6;
        int e4 = f & 63;
        *(float4*)&t2[vg][e4] = *(const float4*)(srpe + (size_t)v0 * Gdim * Edim + f);
    }
    __syncthreads();
    const int e = tid & 63;
#pragma unroll
    for (int h = 0; h < 2; ++h) {
        const int vv = (tid >> 6) * 2 + h;
        uint4 o[2];
#pragma unroll
        for (int c = 0; c < 2; ++c) {
            o[c].x = pk2(t2[vv * 32 + c * 16 + 0][e],  t2[vv * 32 + c * 16 + 1][e]);
            o[c].y = pk2(t2[vv * 32 + c * 16 + 2][e],  t2[vv * 32 + c * 16 + 3][e]);
            o[c].z = pk2(t2[vv * 32 + c * 16 + 4][e],  t2[vv * 32 + c * 16 + 5][e]);
            o[c].w = pk2(t2[vv * 32 + c * 16 + 6][e],  t2[vv * 32 + c * 16 + 7][e]);
        }
        uint4 o2[2];
#pragma unroll
        for (int c = 0; c < 2; ++c) {
            o2[c].x = pk2(t2[vv * 32 + c * 16 + 8][e],  t2[vv * 32 + c * 16 + 9][e]);
            o2[c].y = pk2(t2[vv * 32 + c * 16 + 10][e], t2[vv * 32 + c * 16 + 11][e]);
            o2[c].z = pk2(t2[vv * 32 + c * 16 + 12][e], t2[vv * 32 + c * 16 + 13][e]);
            o2[c].w = pk2(t2[vv * 32 + c * 16 + 14][e], t2[vv * 32 + c * 16 + 15][e]);
        }
        ushort* dst = Se + ((size_t)(e * Vdim) + v0 + vv) * Gdim;
        *(uint4*)(dst + 0)  = o[0];
        *(uint4*)(dst + 8)  = o2[0];
        *(uint4*)(dst + 16) = o[1];
        *(uint4*)(dst + 24) = o2[1];
    }
}

// ---------------------------------------------------------------------------
// K2: MFMA graph-mix, 2-phase pipelined (T3-min), XCD-chunked, swizzled LDS.
// Per wg: fixed e, 192 bt x 128 v, K over i (step 32, double-buffered).
// Output: xrel bf16 [e][bt][v] into d_out.
// ---------------------------------------------------------------------------
__global__ __launch_bounds__(256) void k_relmix_mfma(const ushort* __restrict__ Xbf,
                                                     const ushort* __restrict__ Se,
                                                     ushort* __restrict__ xrel) {
    __shared__ __align__(16) ushort A_s[2][192 * 32];   // [bt][i], src-swizzled
    __shared__ __align__(16) ushort Si_s[2][32 * 32];   // [i][g],  src-swizzled
    __shared__ __align__(16) ushort Sv_s[128 * 32];     // [v][g],  linear
    __shared__ __align__(16) ushort R_s[128 * 40];      // [v][i],  80 B pitch

    const int tid = threadIdx.x;
    const int l = tid & 63;
    const int w = tid >> 6;              // wave 0..3
    const int wm = w >> 1;               // bt half (96 each)
    const int wn = w & 1;                // v half (64 each)

    // XCD-chunked swizzle: each XCD gets 128 consecutive wg = 8 e values,
    // so the per-e A panel (768 KB) stays resident in that XCD's L2.
    const int raw = blockIdx.x;                       // 0..1023
    const int wg  = (raw & 7) * 128 + (raw >> 3);     // bijective
    const int e   = wg >> 4;
    const int btT = (wg >> 3) & 1;
    const int vT  = wg & 7;
    const int bt0 = btT * 192;
    const int v0  = vT * 128;

    const int lr  = l >> 2;                           // sub-row in 16-row chunk
    const int lc  = ((l & 3) ^ (lr & 3)) * 8;         // swizzled col (ushort)
    const int lcL = (l & 3) * 8;                      // linear col

    // ---- prologue staging: Sv (linear), A[0], Si[0] (src-swizzled)
    {
        const ushort* gSv = Se + ((size_t)e * Vdim + v0) * Gdim;
#pragma unroll
        for (int c = 0; c < 2; ++c) {
            int chunk = w * 2 + c;
            __builtin_amdgcn_global_load_lds(gSv + (size_t)(chunk * 16 + lr) * Gdim + lcL,
                                             &Sv_s[chunk * 512], 16, 0, 0);
        }
    }
    const ushort* gA  = Xbf + ((size_t)(e * BT + bt0)) * Vdim;
    const ushort* gSi = Se + (size_t)e * Vdim * Gdim;
#pragma unroll
    for (int c = 0; c < 3; ++c) {
        int chunk = w * 3 + c;
        __builtin_amdgcn_global_load_lds(gA + (size_t)(chunk * 16 + lr) * Vdim + lc,
                                         &A_s[0][chunk * 512], 16, 0, 0);
    }
    if (w < 2)
        __builtin_amdgcn_global_load_lds(gSi + (size_t)(w * 16 + lr) * Gdim + lc,
                                         &Si_s[0][w * 512], 16, 0, 0);
    __syncthreads();

    // ---- Sv fragments: step-invariant, hoisted to registers
    bf16x8 svF[2];
#pragma unroll
    for (int k = 0; k < 2; ++k) {
        const int vloc = (2 * w + k) * 16 + (l & 15);
        svF[k] = *(const bf16x8*)&Sv_s[vloc * 32 + (l >> 4) * 8];
    }

    f32x4 acc[6][4];
    const f32x4 fz = {0.f, 0.f, 0.f, 0.f};
#pragma unroll
    for (int m = 0; m < 6; ++m)
#pragma unroll
        for (int n = 0; n < 4; ++n) acc[m][n] = fz;

    for (int t = 0; t < 32; ++t) {
        const int cur = t & 1;
        // ---- issue next-tile stage (overlaps with this tile's compute)
        if (t < 31) {
            const int i0n = (t + 1) * 32;
#pragma unroll
            for (int c = 0; c < 3; ++c) {
                int chunk = w * 3 + c;
                __builtin_amdgcn_global_load_lds(gA + (size_t)(chunk * 16 + lr) * Vdim + i0n + lc,
                                                 &A_s[cur ^ 1][chunk * 512], 16, 0, 0);
            }
            if (w < 2)
                __builtin_amdgcn_global_load_lds(gSi + (size_t)(i0n + w * 16 + lr) * Gdim + lc,
                                                 &Si_s[cur ^ 1][w * 512], 16, 0, 0);
        }
        // ---- relation tile: R[v][i] = relu(Si . Sv^T), swizzled Si reads
        {
            const int r0 = (l & 15), r1 = 16 + (l & 15);
            const int kg = l >> 4;
            bf16x8 siF0 = *(const bf16x8*)&Si_s[cur][r0 * 32 + (kg ^ (r0 & 3)) * 8];
            bf16x8 siF1 = *(const bf16x8*)&Si_s[cur][r1 * 32 + (kg ^ (r1 & 3)) * 8];
#pragma unroll
            for (int k = 0; k < 2; ++k) {
                const int vloc = (2 * w + k) * 16 + (l & 15);
                f32x4 d0 = __builtin_amdgcn_mfma_f32_16x16x32_bf16(siF0, svF[k], fz, 0, 0, 0);
                f32x4 d1 = __builtin_amdgcn_mfma_f32_16x16x32_bf16(siF1, svF[k], fz, 0, 0, 0);
                const int ib0 = kg * 4;
                uint2 w0, w1;
                w0.x = pk2(fmaxf(d0[0], 0.f), fmaxf(d0[1], 0.f));
                w0.y = pk2(fmaxf(d0[2], 0.f), fmaxf(d0[3], 0.f));
                w1.x = pk2(fmaxf(d1[0], 0.f), fmaxf(d1[1], 0.f));
                w1.y = pk2(fmaxf(d1[2], 0.f), fmaxf(d1[3], 0.f));
                *(uint2*)&R_s[vloc * 40 + ib0]      = w0;
                *(uint2*)&R_s[vloc * 40 + 16 + ib0] = w1;
            }
        }
        // ---- A fragments (swizzled reads of current buffer)
        bf16x8 aF[6];
#pragma unroll
        for (int m = 0; m < 6; ++m) {
            const int row = wm * 96 + m * 16 + (l & 15);
            aF[m] = *(const bf16x8*)&A_s[cur][row * 32 + (((l >> 4) ^ (row & 3))) * 8];
        }
        // barrier #1: R_s writes + aF reads drained (LDS only; VMEM stays in flight)
        asm volatile("s_waitcnt lgkmcnt(0)" ::: "memory");
        __builtin_amdgcn_sched_barrier(0);
        __builtin_amdgcn_s_barrier();
        __builtin_amdgcn_sched_barrier(0);
        // ---- 24 main MFMAs
#pragma unroll
        for (int n = 0; n < 4; ++n) {
            bf16x8 bF = *(const bf16x8*)&R_s[(wn * 64 + n * 16 + (l & 15)) * 40 + (l >> 4) * 8];
#pragma unroll
            for (int m = 0; m < 6; ++m)
                acc[m][n] = __builtin_amdgcn_mfma_f32_16x16x32_bf16(aF[m], bF, acc[m][n], 0, 0, 0);
        }
        // barrier #2: next tile fully landed in LDS; all reads of cur done
        asm volatile("s_waitcnt vmcnt(0)" ::: "memory");
        __builtin_amdgcn_sched_barrier(0);
        __builtin_amdgcn_s_barrier();
        __builtin_amdgcn_sched_barrier(0);
    }

    // ---- epilogue: bf16 stores, v-contiguous across lanes (32 B runs)
#pragma unroll
    for (int m = 0; m < 6; ++m) {
        const int btl = bt0 + wm * 96 + m * 16 + (l >> 4) * 4;
#pragma unroll
        for (int j = 0; j < 4; ++j) {
            ushort* row = xrel + ((size_t)(e * BT) + btl + j) * Vdim + v0;
#pragma unroll
            for (int n = 0; n < 4; ++n)
                row[wn * 64 + n * 16 + (l & 15)] = f2bf(acc[m][n][j]);
        }
    }
}

// ---------------------------------------------------------------------------
// K2.5: xrT[bt][v][e] = xrel[e][bt][v]   (bf16 -> bf16, XOR-swizzled LDS)
// ---------------------------------------------------------------------------
__global__ __launch_bounds__(256) void k_xrelT(const ushort* __restrict__ xr,
                                               ushort* __restrict__ xrT) {
    __shared__ uint t[64 * 256];         // word (e, vpair), swizzled
    const int tid = threadIdx.x;
    const int bt = blockIdx.x >> 1;
    const int v0 = (blockIdx.x & 1) * 512;
    {
        const int e = tid >> 2, q = tid & 3;
        const ushort* src = xr + ((size_t)(e * BT) + bt) * Vdim + v0 + q * 128;
#pragma unroll
        for (int c = 0; c < 16; ++c) {
            uint4 x = *(const uint4*)(src + c * 8);
            int p = q * 64 + c * 4;
            int sw = ((e & 3) << 3) ^ ((p >> 6) << 2);
            *(uint4*)&t[e * 256 + (p ^ sw)] = x;
        }
    }
    __syncthreads();
    {
        const int p = tid;               // v-pair 0..255
        uint lw[32], hw[32];
#pragma unroll
        for (int e2 = 0; e2 < 32; ++e2) {
            const int ea = 2 * e2, eb = 2 * e2 + 1;
            uint xa = t[ea * 256 + (p ^ (((ea & 3) << 3) ^ ((p >> 6) << 2)))];
            uint xb = t[eb * 256 + (p ^ (((eb & 3) << 3) ^ ((p >> 6) << 2)))];
            lw[e2] = (xa & 0xffffu) | (xb << 16);
            hw[e2] = (xa >> 16) | (xb & 0xffff0000u);
        }
        ushort* d0 = xrT + ((size_t)(bt * Vdim) + v0 + 2 * p) * Edim;
        ushort* d1 = d0 + Edim;
#pragma unroll
        for (int c = 0; c < 8; ++c) {
            uint4 o; o.x = lw[c*4]; o.y = lw[c*4+1]; o.z = lw[c*4+2]; o.w = lw[c*4+3];
            *(uint4*)(d0 + c * 8) = o;
        }
#pragma unroll
        for (int c = 0; c < 8; ++c) {
            uint4 o; o.x = hw[c*4]; o.y = hw[c*4+1]; o.z = hw[c*4+2]; o.w = hw[c*4+3];
            *(uint4*)(d1 + c * 8) = o;
        }
    }
}

// ---------------------------------------------------------------------------
// K3: per (t,v): y[b,e] = leaky( sum_f xl[b,f] * W[t,v,f,e] + bias )
// MFMA version: W staged f32 via global_load_lds, bf16 frags built in-reg.
// ---------------------------------------------------------------------------
__global__ __launch_bounds__(256) void k_final(const ushort* __restrict__ xrT,
        const int* __restrict__ n_route, const int* __restrict__ s_week,
        const int* __restrict__ s_day,  const float* __restrict__ sape,
        const float* __restrict__ dow,  const float* __restrict__ tod,
        const float* __restrict__ Wc,   const float* __restrict__ bias,
        float* __restrict__ out) {
    __shared__ __align__(16) float  Wl[12288];      // [f][e] f32, 48 KB, linear
    __shared__ __align__(16) ushort xs[32 * 208];   // xl bf16 [b][f], pitch 208
    __shared__ float bl[64];
    const int tid = threadIdx.x;
    const int l = tid & 63, w = tid >> 6;
    const int v = blockIdx.x & (Vdim - 1);
    const int t = blockIdx.x >> 10;

    // ---- stage W (48 KB, coalesced, zero-VGPR)
    const float* Wg = Wc + ((size_t)(t * Vdim + v)) * 192 * Edim;
#pragma unroll
    for (int c = 0; c < 12; ++c) {
        int chunk = w * 12 + c;
        __builtin_amdgcn_global_load_lds(Wg + chunk * 256 + l * 4, &Wl[chunk * 256], 16, 0, 0);
    }
    // ---- build xl bf16 [b][f]: [x_rel | sape | dow+tod]
    {
        const int b  = tid >> 3;
        const int e0 = (tid & 7) * 8;
        const int bt = b * Tdim + t;
        uint4 raw = *(const uint4*)(xrT + ((size_t)(bt * Vdim) + v) * Edim + e0);
        *(uint4*)&xs[b * 208 + e0] = raw;
        const int r  = n_route[b * Vdim + v];
        const float* sp = sape + ((size_t)(r * Tdim) + t) * Edim + e0;
        const int wd = s_week[bt], dd = s_day[bt];
        const float* dp = dow + ((size_t)(wd * Vdim) + v) * Edim + e0;
        const float* tp = tod + ((size_t)(dd * Vdim) + v) * Edim + e0;
        uint4 o1, o2;
        o1.x = pk2(sp[0], sp[1]); o1.y = pk2(sp[2], sp[3]);
        o1.z = pk2(sp[4], sp[5]); o1.w = pk2(sp[6], sp[7]);
        *(uint4*)&xs[b * 208 + 64 + e0] = o1;
        o2.x = pk2(dp[0] + tp[0], dp[1] + tp[1]);
        o2.y = pk2(dp[2] + tp[2], dp[3] + tp[3]);
        o2.z = pk2(dp[4] + tp[4], dp[5] + tp[5]);
        o2.w = pk2(dp[6] + tp[6], dp[7] + tp[7]);
        *(uint4*)&xs[b * 208 + 128 + e0] = o2;
    }
    if (tid < 64) bl[tid] = bias[((size_t)(t * Vdim) + v) * Edim + tid];
    __syncthreads();

    // ---- MFMA: wave w owns (mt = w>>1, nt in {2*(w&1), 2*(w&1)+1})
    const int mt  = w >> 1;
    const int ntb = (w & 1) * 2;
    const f32x4 fz = {0.f, 0.f, 0.f, 0.f};
    f32x4 acc[2] = {fz, fz};
    const int arow = (mt * 16 + (l & 15)) * 208 + (l >> 4) * 8;
#pragma unroll
    for (int ks = 0; ks < 6; ++ks) {
        bf16x8 aF = *(const bf16x8*)&xs[arow + ks * 32];
        const int fbase = ks * 32 + (l >> 4) * 8;
#pragma unroll
        for (int ni = 0; ni < 2; ++ni) {
            const int ecol = (ntb + ni) * 16 + (l & 15);
            uint4 uu;
            uu.x = pk2(Wl[(fbase + 0) * 64 + ecol], Wl[(fbase + 1) * 64 + ecol]);
            uu.y = pk2(Wl[(fbase + 2) * 64 + ecol], Wl[(fbase + 3) * 64 + ecol]);
            uu.z = pk2(Wl[(fbase + 4) * 64 + ecol], Wl[(fbase + 5) * 64 + ecol]);
            uu.w = pk2(Wl[(fbase + 6) * 64 + ecol], Wl[(fbase + 7) * 64 + ecol]);
            bf16x8 bF;
            __builtin_memcpy(&bF, &uu, 16);
            acc[ni] = __builtin_amdgcn_mfma_f32_16x16x32_bf16(aF, bF, acc[ni], 0, 0, 0);
        }
    }
    // ---- epilogue: bias + leaky, coalesced 64 B runs per 16 lanes
    const int brow = mt * 16 + (l >> 4) * 4;
#pragma unroll
    for (int ni = 0; ni < 2; ++ni) {
        const int ecol = (ntb + ni) * 16 + (l & 15);
        const float bv = bl[ecol];
#pragma unroll
        for (int j = 0; j < 4; ++j) {
            float s = acc[ni][j] + bv;
            s = s > 0.f ? s : 0.3f * s;
            out[(size_t)(brow + j) * (Tdim * Vdim * Edim)
                + (size_t)t * (Vdim * Edim) + v * Edim + ecol] = s;
        }
    }
}

// ---------------------------------------------------------------------------
extern "C" void kernel_launch(void* const* d_in, const int* in_sizes, int n_in,
                              void* d_out, int out_size, void* d_ws, size_t ws_size,
                              hipStream_t stream) {
    const float* inputs = (const float*)d_in[0];
    const int*   n_route= (const int*)d_in[1];
    const int*   s_week = (const int*)d_in[2];
    const int*   s_day  = (const int*)d_in[3];
    const float* srpe   = (const float*)d_in[4];
    const float* sape   = (const float*)d_in[5];
    const float* dow    = (const float*)d_in[6];
    const float* tod    = (const float*)d_in[7];
    const float* Wc     = (const float*)d_in[8];
    const float* bias   = (const float*)d_in[9];

    // ws layout: Xbf [0, 48MB) ; Se [48MB, 52MB) ; xrT reuses [0, 48MB) after K2
    ushort* Xbf  = (ushort*)d_ws;
    ushort* Se   = (ushort*)((char*)d_ws + (size_t)Edim * BT * Vdim * 2);
    ushort* xrel = (ushort*)d_out;               // bf16 scratch inside d_out
    ushort* xrT  = (ushort*)d_ws;                // overwrites Xbf (dead after K2)
    float*  out  = (float*)d_out;

    k_xpose<<<dim3(BT * 16), dim3(256), 0, stream>>>(inputs, Xbf);
    k_se<<<dim3(Vdim / 8), dim3(256), 0, stream>>>(srpe, Se);
    k_relmix_mfma<<<dim3(1024), dim3(256), 0, stream>>>(Xbf, Se, xrel);
    k_xrelT<<<dim3(BT * 2), dim3(256), 0, stream>>>(xrel, xrT);
    k_final<<<dim3(Tdim * Vdim), dim3(256), 0, stream>>>(
        xrT, n_route, s_week, s_day, sape, dow, tod, Wc, bias, out);
}

// Round 4
// 321.939 us; speedup vs baseline: 3.7335x; 1.0078x over previous
//
#include <hip/hip_runtime.h>
#include <stdint.h>

#define Bdim 32
#define Tdim 12
#define Vdim 1024
#define Edim 64
#define Gdim 32
#define BT   384   // B*T

typedef __attribute__((ext_vector_type(8))) short bf16x8;
typedef __attribute__((ext_vector_type(4))) float f32x4;

__device__ __forceinline__ ushort f2bf(float f) {
    uint u = __float_as_uint(f);
    u += 0x7fffu + ((u >> 16) & 1u);      // RNE
    return (ushort)(u >> 16);
}
__device__ __forceinline__ float bf2f_lo(uint u) { return __uint_as_float(u << 16); }
__device__ __forceinline__ float bf2f_hi(uint u) { return __uint_as_float(u & 0xffff0000u); }
__device__ __forceinline__ uint pk2(float a, float b) {
    return (uint)f2bf(a) | ((uint)f2bf(b) << 16);
}

// ---------------------------------------------------------------------------
// K1a: Xbf[e][bt][i] (bf16) = inputs[bt][i][e] (f32)
// ---------------------------------------------------------------------------
__global__ __launch_bounds__(256) void k_xpose(const float* __restrict__ in,
                                               ushort* __restrict__ Xbf) {
    __shared__ float tile[64][68];
    const int bt = blockIdx.x >> 4;
    const int i0 = (blockIdx.x & 15) << 6;
    const int r  = threadIdx.x >> 2;     // i-local on load, e on store
    const int q  = threadIdx.x & 3;
    const float* src = in + ((size_t)(bt * Vdim) + i0 + r) * Edim + q * 16;
#pragma unroll
    for (int k = 0; k < 4; ++k)
        *(float4*)&tile[r][q * 16 + 4 * k] = *(const float4*)(src + 4 * k);
    __syncthreads();
    const int e  = r;
    const int ib = q * 16;
    uint4 s0, s1;
    s0.x = pk2(tile[ib + 0][e],  tile[ib + 1][e]);
    s0.y = pk2(tile[ib + 2][e],  tile[ib + 3][e]);
    s0.z = pk2(tile[ib + 4][e],  tile[ib + 5][e]);
    s0.w = pk2(tile[ib + 6][e],  tile[ib + 7][e]);
    s1.x = pk2(tile[ib + 8][e],  tile[ib + 9][e]);
    s1.y = pk2(tile[ib + 10][e], tile[ib + 11][e]);
    s1.z = pk2(tile[ib + 12][e], tile[ib + 13][e]);
    s1.w = pk2(tile[ib + 14][e], tile[ib + 15][e]);
    ushort* dst = Xbf + ((size_t)(e * BT) + bt) * Vdim + i0 + ib;
    *(uint4*)dst = s0;
    *(uint4*)(dst + 8) = s1;
}

// ---------------------------------------------------------------------------
// K1b: Se[e][v][g] (bf16) = srpe[v][g][e] (f32)
// ---------------------------------------------------------------------------
__global__ __launch_bounds__(256) void k_se(const float* __restrict__ srpe,
                                            ushort* __restrict__ Se) {
    __shared__ float t2[256][65];        // [vv*32+g][e], pad 65
    const int tid = threadIdx.x;
    const int v0 = blockIdx.x * 8;
#pragma unroll
    for (int c = 0; c < 16; ++c) {
        int f = (c * 256 + tid) * 4;     // flat f32 idx within block slab
        int vg = f >> 6;
        int e4 = f & 63;
        *(float4*)&t2[vg][e4] = *(const float4*)(srpe + (size_t)v0 * Gdim * Edim + f);
    }
    __syncthreads();
    const int e = tid & 63;
#pragma unroll
    for (int h = 0; h < 2; ++h) {
        const int vv = (tid >> 6) * 2 + h;
        uint4 o[2];
#pragma unroll
        for (int c = 0; c < 2; ++c) {
            o[c].x = pk2(t2[vv * 32 + c * 16 + 0][e],  t2[vv * 32 + c * 16 + 1][e]);
            o[c].y = pk2(t2[vv * 32 + c * 16 + 2][e],  t2[vv * 32 + c * 16 + 3][e]);
            o[c].z = pk2(t2[vv * 32 + c * 16 + 4][e],  t2[vv * 32 + c * 16 + 5][e]);
            o[c].w = pk2(t2[vv * 32 + c * 16 + 6][e],  t2[vv * 32 + c * 16 + 7][e]);
        }
        uint4 o2[2];
#pragma unroll
        for (int c = 0; c < 2; ++c) {
            o2[c].x = pk2(t2[vv * 32 + c * 16 + 8][e],  t2[vv * 32 + c * 16 + 9][e]);
            o2[c].y = pk2(t2[vv * 32 + c * 16 + 10][e], t2[vv * 32 + c * 16 + 11][e]);
            o2[c].z = pk2(t2[vv * 32 + c * 16 + 12][e], t2[vv * 32 + c * 16 + 13][e]);
            o2[c].w = pk2(t2[vv * 32 + c * 16 + 14][e], t2[vv * 32 + c * 16 + 15][e]);
        }
        ushort* dst = Se + ((size_t)(e * Vdim) + v0 + vv) * Gdim;
        *(uint4*)(dst + 0)  = o[0];
        *(uint4*)(dst + 8)  = o2[0];
        *(uint4*)(dst + 16) = o[1];
        *(uint4*)(dst + 24) = o2[1];
    }
}

// ---------------------------------------------------------------------------
// K2: MFMA graph-mix, depth-2 counted-vmcnt pipeline (T3+T4), 1 barrier/step.
// Per wg: fixed e, 192 bt x 128 v, K over i (step 32, A/Si triple-buffered,
// R computed one step ahead, double-buffered). Sv in registers.
// Output: xrel bf16 [e][bt][v] into d_out.
// ---------------------------------------------------------------------------
__global__ __launch_bounds__(256, 2) void k_relmix_mfma(const ushort* __restrict__ Xbf,
                                                        const ushort* __restrict__ Se,
                                                        ushort* __restrict__ xrel) {
    __shared__ __align__(16) ushort A_s[3][192 * 32];   // [bt][i], src-swizzled
    __shared__ __align__(16) ushort Si_s[3][32 * 32];   // [i][g],  src-swizzled
    __shared__ __align__(16) ushort R_s[2][128 * 40];   // [v][i],  80 B pitch

    const int tid = threadIdx.x;
    const int l = tid & 63;
    const int w = tid >> 6;              // wave 0..3
    const int wm = w >> 1;               // bt half (96 each)
    const int wn = w & 1;                // v half (64 each)

    // XCD-chunked swizzle: 128 consecutive wg (8 e values) per XCD.
    const int raw = blockIdx.x;                       // 0..1023
    const int wg  = (raw & 7) * 128 + (raw >> 3);     // bijective
    const int e   = wg >> 4;
    const int btT = (wg >> 3) & 1;
    const int vT  = wg & 7;
    const int bt0 = btT * 192;
    const int v0  = vT * 128;

    const int lr  = l >> 2;                           // sub-row in 16-row chunk
    const int lc  = ((l & 3) ^ (lr & 3)) * 8;         // swizzled col (ushort)

    const ushort* gA  = Xbf + ((size_t)(e * BT + bt0)) * Vdim;
    const ushort* gSi = Se + (size_t)e * Vdim * Gdim;

    // ---- Sv fragments: direct global -> regs (coalesced 1 KB per (w,k))
    bf16x8 svF[2];
    {
        const ushort* gSv = Se + ((size_t)e * Vdim + v0) * Gdim;
#pragma unroll
        for (int k = 0; k < 2; ++k) {
            const int vloc = (2 * w + k) * 16 + (l & 15);
            svF[k] = *(const bf16x8*)(gSv + (size_t)vloc * Gdim + (l >> 4) * 8);
        }
    }
    __builtin_amdgcn_sched_barrier(0);   // pin svF loads before the lds-loads

    // ---- prologue: issue Si0,A0,Si1,A1 (Si before A each step!)
    if (w < 2)
        __builtin_amdgcn_global_load_lds(gSi + (size_t)(0 + w * 16 + lr) * Gdim + lc,
                                         &Si_s[0][w * 512], 16, 0, 0);
#pragma unroll
    for (int c = 0; c < 3; ++c) {
        int chunk = w * 3 + c;
        __builtin_amdgcn_global_load_lds(gA + (size_t)(chunk * 16 + lr) * Vdim + 0 + lc,
                                         &A_s[0][chunk * 512], 16, 0, 0);
    }
    if (w < 2)
        __builtin_amdgcn_global_load_lds(gSi + (size_t)(32 + w * 16 + lr) * Gdim + lc,
                                         &Si_s[1][w * 512], 16, 0, 0);
#pragma unroll
    for (int c = 0; c < 3; ++c) {
        int chunk = w * 3 + c;
        __builtin_amdgcn_global_load_lds(gA + (size_t)(chunk * 16 + lr) * Vdim + 32 + lc,
                                         &A_s[1][chunk * 512], 16, 0, 0);
    }
    // wait: leave only newest A tile in flight -> Si0,A0,Si1 (and svF) landed
    asm volatile("s_waitcnt vmcnt(3)" ::: "memory");
    __builtin_amdgcn_sched_barrier(0);
    __builtin_amdgcn_s_barrier();
    __builtin_amdgcn_sched_barrier(0);

    const f32x4 fz = {0.f, 0.f, 0.f, 0.f};

    // ---- relation-tile compute: R[rb] = relu(Si[sb] . Sv^T)
    auto computeR = [&](int sb, int rb) {
        const int r0 = (l & 15), r1 = 16 + (l & 15);
        const int kg = l >> 4;
        bf16x8 siF0 = *(const bf16x8*)&Si_s[sb][r0 * 32 + (kg ^ (r0 & 3)) * 8];
        bf16x8 siF1 = *(const bf16x8*)&Si_s[sb][r1 * 32 + (kg ^ (r1 & 3)) * 8];
#pragma unroll
        for (int k = 0; k < 2; ++k) {
            const int vloc = (2 * w + k) * 16 + (l & 15);
            f32x4 d0 = __builtin_amdgcn_mfma_f32_16x16x32_bf16(siF0, svF[k], fz, 0, 0, 0);
            f32x4 d1 = __builtin_amdgcn_mfma_f32_16x16x32_bf16(siF1, svF[k], fz, 0, 0, 0);
            uint2 w0, w1;
            w0.x = pk2(fmaxf(d0[0], 0.f), fmaxf(d0[1], 0.f));
            w0.y = pk2(fmaxf(d0[2], 0.f), fmaxf(d0[3], 0.f));
            w1.x = pk2(fmaxf(d1[0], 0.f), fmaxf(d1[1], 0.f));
            w1.y = pk2(fmaxf(d1[2], 0.f), fmaxf(d1[3], 0.f));
            *(uint2*)&R_s[rb][vloc * 40 + kg * 4]      = w0;
            *(uint2*)&R_s[rb][vloc * 40 + 16 + kg * 4] = w1;
        }
    };

    // prologue R[0]
    computeR(0, 0);
    asm volatile("s_waitcnt lgkmcnt(0)" ::: "memory");
    __builtin_amdgcn_sched_barrier(0);
    __builtin_amdgcn_s_barrier();
    __builtin_amdgcn_sched_barrier(0);

    f32x4 acc[6][4];
#pragma unroll
    for (int m = 0; m < 6; ++m)
#pragma unroll
        for (int n = 0; n < 4; ++n) acc[m][n] = fz;

    int c0 = 0, c1 = 1, c2 = 2;          // A/Si buffers: cur, next, future
    int rc = 0, rn = 1;                  // R buffers: cur, next

    for (int t = 0; t < 32; ++t) {
        // ---- issue future loads (Si first, then A: keeps vmcnt(3) semantics)
        const int i0f = ((t + 2) & 31) * 32;   // wraps at tail: valid, never read
        if (w < 2)
            __builtin_amdgcn_global_load_lds(gSi + (size_t)(i0f + w * 16 + lr) * Gdim + lc,
                                             &Si_s[c2][w * 512], 16, 0, 0);
#pragma unroll
        for (int c = 0; c < 3; ++c) {
            int chunk = w * 3 + c;
            __builtin_amdgcn_global_load_lds(gA + (size_t)(chunk * 16 + lr) * Vdim + i0f + lc,
                                             &A_s[c2][chunk * 512], 16, 0, 0);
        }
        // ---- R[t+1] from Si[c1] (landed at end of prior step)
        computeR(c1, rn);
        // ---- A fragments (swizzled reads of current buffer)
        bf16x8 aF[6];
#pragma unroll
        for (int m = 0; m < 6; ++m) {
            const int row = wm * 96 + m * 16 + (l & 15);
            aF[m] = *(const bf16x8*)&A_s[c0][row * 32 + (((l >> 4) ^ (row & 3))) * 8];
        }
        // ---- 24 main MFMAs reading R[rc]
        __builtin_amdgcn_s_setprio(1);
#pragma unroll
        for (int n = 0; n < 4; ++n) {
            bf16x8 bF = *(const bf16x8*)&R_s[rc][(wn * 64 + n * 16 + (l & 15)) * 40 + (l >> 4) * 8];
#pragma unroll
            for (int m = 0; m < 6; ++m)
                acc[m][n] = __builtin_amdgcn_mfma_f32_16x16x32_bf16(aF[m], bF, acc[m][n], 0, 0, 0);
        }
        __builtin_amdgcn_s_setprio(0);
        // ---- single barrier: A[t+1]+Si[t+2] landed (vmcnt(3)), LDS ops drained
        asm volatile("s_waitcnt vmcnt(3) lgkmcnt(0)" ::: "memory");
        __builtin_amdgcn_sched_barrier(0);
        __builtin_amdgcn_s_barrier();
        __builtin_amdgcn_sched_barrier(0);
        // ---- rotate buffers
        int tmp = c0; c0 = c1; c1 = c2; c2 = tmp;
        tmp = rc; rc = rn; rn = tmp;
    }

    // ---- epilogue: bf16 stores, v-contiguous across lanes (32 B runs)
#pragma unroll
    for (int m = 0; m < 6; ++m) {
        const int btl = bt0 + wm * 96 + m * 16 + (l >> 4) * 4;
#pragma unroll
        for (int j = 0; j < 4; ++j) {
            ushort* row = xrel + ((size_t)(e * BT) + btl + j) * Vdim + v0;
#pragma unroll
            for (int n = 0; n < 4; ++n)
                row[wn * 64 + n * 16 + (l & 15)] = f2bf(acc[m][n][j]);
        }
    }
}

// ---------------------------------------------------------------------------
// K2.5: xrT[bt][v][e] = xrel[e][bt][v]   (bf16 -> bf16, XOR-swizzled LDS)
// ---------------------------------------------------------------------------
__global__ __launch_bounds__(256) void k_xrelT(const ushort* __restrict__ xr,
                                               ushort* __restrict__ xrT) {
    __shared__ uint t[64 * 256];         // word (e, vpair), swizzled
    const int tid = threadIdx.x;
    const int bt = blockIdx.x >> 1;
    const int v0 = (blockIdx.x & 1) * 512;
    {
        const int e = tid >> 2, q = tid & 3;
        const ushort* src = xr + ((size_t)(e * BT) + bt) * Vdim + v0 + q * 128;
#pragma unroll
        for (int c = 0; c < 16; ++c) {
            uint4 x = *(const uint4*)(src + c * 8);
            int p = q * 64 + c * 4;
            int sw = ((e & 3) << 3) ^ ((p >> 6) << 2);
            *(uint4*)&t[e * 256 + (p ^ sw)] = x;
        }
    }
    __syncthreads();
    {
        const int p = tid;               // v-pair 0..255
        uint lw[32], hw[32];
#pragma unroll
        for (int e2 = 0; e2 < 32; ++e2) {
            const int ea = 2 * e2, eb = 2 * e2 + 1;
            uint xa = t[ea * 256 + (p ^ (((ea & 3) << 3) ^ ((p >> 6) << 2)))];
            uint xb = t[eb * 256 + (p ^ (((eb & 3) << 3) ^ ((p >> 6) << 2)))];
            lw[e2] = (xa & 0xffffu) | (xb << 16);
            hw[e2] = (xa >> 16) | (xb & 0xffff0000u);
        }
        ushort* d0 = xrT + ((size_t)(bt * Vdim) + v0 + 2 * p) * Edim;
        ushort* d1 = d0 + Edim;
#pragma unroll
        for (int c = 0; c < 8; ++c) {
            uint4 o; o.x = lw[c*4]; o.y = lw[c*4+1]; o.z = lw[c*4+2]; o.w = lw[c*4+3];
            *(uint4*)(d0 + c * 8) = o;
        }
#pragma unroll
        for (int c = 0; c < 8; ++c) {
            uint4 o; o.x = hw[c*4]; o.y = hw[c*4+1]; o.z = hw[c*4+2]; o.w = hw[c*4+3];
            *(uint4*)(d1 + c * 8) = o;
        }
    }
}

// ---------------------------------------------------------------------------
// K3: per (t,v): y[b,e] = leaky( sum_f xl[b,f] * W[t,v,f,e] + bias )
// MFMA version: W staged f32 via global_load_lds, bf16 frags built in-reg.
// ---------------------------------------------------------------------------
__global__ __launch_bounds__(256) void k_final(const ushort* __restrict__ xrT,
        const int* __restrict__ n_route, const int* __restrict__ s_week,
        const int* __restrict__ s_day,  const float* __restrict__ sape,
        const float* __restrict__ dow,  const float* __restrict__ tod,
        const float* __restrict__ Wc,   const float* __restrict__ bias,
        float* __restrict__ out) {
    __shared__ __align__(16) float  Wl[12288];      // [f][e] f32, 48 KB, linear
    __shared__ __align__(16) ushort xs[32 * 208];   // xl bf16 [b][f], pitch 208
    __shared__ float bl[64];
    const int tid = threadIdx.x;
    const int l = tid & 63, w = tid >> 6;
    const int v = blockIdx.x & (Vdim - 1);
    const int t = blockIdx.x >> 10;

    // ---- stage W (48 KB, coalesced, zero-VGPR)
    const float* Wg = Wc + ((size_t)(t * Vdim + v)) * 192 * Edim;
#pragma unroll
    for (int c = 0; c < 12; ++c) {
        int chunk = w * 12 + c;
        __builtin_amdgcn_global_load_lds(Wg + chunk * 256 + l * 4, &Wl[chunk * 256], 16, 0, 0);
    }
    // ---- build xl bf16 [b][f]: [x_rel | sape | dow+tod]
    {
        const int b  = tid >> 3;
        const int e0 = (tid & 7) * 8;
        const int bt = b * Tdim + t;
        uint4 raw = *(const uint4*)(xrT + ((size_t)(bt * Vdim) + v) * Edim + e0);
        *(uint4*)&xs[b * 208 + e0] = raw;
        const int r  = n_route[b * Vdim + v];
        const float* sp = sape + ((size_t)(r * Tdim) + t) * Edim + e0;
        const int wd = s_week[bt], dd = s_day[bt];
        const float* dp = dow + ((size_t)(wd * Vdim) + v) * Edim + e0;
        const float* tp = tod + ((size_t)(dd * Vdim) + v) * Edim + e0;
        uint4 o1, o2;
        o1.x = pk2(sp[0], sp[1]); o1.y = pk2(sp[2], sp[3]);
        o1.z = pk2(sp[4], sp[5]); o1.w = pk2(sp[6], sp[7]);
        *(uint4*)&xs[b * 208 + 64 + e0] = o1;
        o2.x = pk2(dp[0] + tp[0], dp[1] + tp[1]);
        o2.y = pk2(dp[2] + tp[2], dp[3] + tp[3]);
        o2.z = pk2(dp[4] + tp[4], dp[5] + tp[5]);
        o2.w = pk2(dp[6] + tp[6], dp[7] + tp[7]);
        *(uint4*)&xs[b * 208 + 128 + e0] = o2;
    }
    if (tid < 64) bl[tid] = bias[((size_t)(t * Vdim) + v) * Edim + tid];
    __syncthreads();

    // ---- MFMA: wave w owns (mt = w>>1, nt in {2*(w&1), 2*(w&1)+1})
    const int mt  = w >> 1;
    const int ntb = (w & 1) * 2;
    const f32x4 fz = {0.f, 0.f, 0.f, 0.f};
    f32x4 acc[2] = {fz, fz};
    const int arow = (mt * 16 + (l & 15)) * 208 + (l >> 4) * 8;
#pragma unroll
    for (int ks = 0; ks < 6; ++ks) {
        bf16x8 aF = *(const bf16x8*)&xs[arow + ks * 32];
        const int fbase = ks * 32 + (l >> 4) * 8;
#pragma unroll
        for (int ni = 0; ni < 2; ++ni) {
            const int ecol = (ntb + ni) * 16 + (l & 15);
            uint4 uu;
            uu.x = pk2(Wl[(fbase + 0) * 64 + ecol], Wl[(fbase + 1) * 64 + ecol]);
            uu.y = pk2(Wl[(fbase + 2) * 64 + ecol], Wl[(fbase + 3) * 64 + ecol]);
            uu.z = pk2(Wl[(fbase + 4) * 64 + ecol], Wl[(fbase + 5) * 64 + ecol]);
            uu.w = pk2(Wl[(fbase + 6) * 64 + ecol], Wl[(fbase + 7) * 64 + ecol]);
            bf16x8 bF;
            __builtin_memcpy(&bF, &uu, 16);
            acc[ni] = __builtin_amdgcn_mfma_f32_16x16x32_bf16(aF, bF, acc[ni], 0, 0, 0);
        }
    }
    // ---- epilogue: bias + leaky, coalesced 64 B runs per 16 lanes
    const int brow = mt * 16 + (l >> 4) * 4;
#pragma unroll
    for (int ni = 0; ni < 2; ++ni) {
        const int ecol = (ntb + ni) * 16 + (l & 15);
        const float bv = bl[ecol];
#pragma unroll
        for (int j = 0; j < 4; ++j) {
            float s = acc[ni][j] + bv;
            s = s > 0.f ? s : 0.3f * s;
            out[(size_t)(brow + j) * (Tdim * Vdim * Edim)
                + (size_t)t * (Vdim * Edim) + v * Edim + ecol] = s;
        }
    }
}

// ---------------------------------------------------------------------------
extern "C" void kernel_launch(void* const* d_in, const int* in_sizes, int n_in,
                              void* d_out, int out_size, void* d_ws, size_t ws_size,
                              hipStream_t stream) {
    const float* inputs = (const float*)d_in[0];
    const int*   n_route= (const int*)d_in[1];
    const int*   s_week = (const int*)d_in[2];
    const int*   s_day  = (const int*)d_in[3];
    const float* srpe   = (const float*)d_in[4];
    const float* sape   = (const float*)d_in[5];
    const float* dow    = (const float*)d_in[6];
    const float* tod    = (const float*)d_in[7];
    const float* Wc     = (const float*)d_in[8];
    const float* bias   = (const float*)d_in[9];

    // ws layout: Xbf [0, 48MB) ; Se [48MB, 52MB) ; xrT reuses [0, 48MB) after K2
    ushort* Xbf  = (ushort*)d_ws;
    ushort* Se   = (ushort*)((char*)d_ws + (size_t)Edim * BT * Vdim * 2);
    ushort* xrel = (ushort*)d_out;               // bf16 scratch inside d_out
    ushort* xrT  = (ushort*)d_ws;                // overwrites Xbf (dead after K2)
    float*  out  = (float*)d_out;

    k_xpose<<<dim3(BT * 16), dim3(256), 0, stream>>>(inputs, Xbf);
    k_se<<<dim3(Vdim / 8), dim3(256), 0, stream>>>(srpe, Se);
    k_relmix_mfma<<<dim3(1024), dim3(256), 0, stream>>>(Xbf, Se, xrel);
    k_xrelT<<<dim3(BT * 2), dim3(256), 0, stream>>>(xrel, xrT);
    k_final<<<dim3(Tdim * Vdim), dim3(256), 0, stream>>>(
        xrT, n_route, s_week, s_day, sape, dow, tod, Wc, bias, out);
}